// Round 4
// baseline (39.136 us; speedup 1.0000x reference)
//
#include <hip/hip_runtime.h>
#include <hip/hip_bf16.h>

namespace {
constexpr int B = 8, T = 12, N = 325, C = 32, K = 100;
constexpr int KPAD = 36;                      // padded LDS row (floats)
constexpr int NPB = 2;                        // n's handled per block
constexpr int NPAIRS = (N + NPB - 1) / NPB;   // 163
constexpr float EPSF = 1e-5f;
constexpr float MIN_NORM = 1e-15f;
}

__device__ __forceinline__ float ldin(const void* p, size_t i, int isb) {
  if (isb) {
    unsigned short u = ((const unsigned short*)p)[i];
    return __uint_as_float(((unsigned int)u) << 16);
  }
  return ((const float*)p)[i];
}

__global__ __launch_bounds__(256) void hcd_kernel(
    const void* __restrict__ x_raw,      // [B,T,N,C]  (fp32 per sniff)
    const void* __restrict__ cw_raw,     // [K,C]
    const void* __restrict__ c_raw,      // [1]
    float* __restrict__ out0,            // [B,N,K]   fp32
    float* __restrict__ out1)            // [B,T,N,K] fp32
{
  __shared__ float yl[K][KPAD];
  __shared__ float y2l[K];
  __shared__ float xl[NPB][T][KPAD];
  __shared__ float x2l[NPB][T];
  __shared__ int stot;

  const int tid = threadIdx.x;
  const int b  = blockIdx.x / NPAIRS;
  const int np = blockIdx.x % NPAIRS;
  const int n0 = np * NPB;

  // ---- dtype sniff on the node buffer ----
  {
    const unsigned short* xr16 = (const unsigned short*)x_raw;
    int cnt = 0;
    for (int i = tid; i < 1024; i += 256) {
      unsigned short v = xr16[2 * i];
      int e = (v >> 7) & 0xFF;
      cnt += (e >= 0x68 && e <= 0x7E) ? 1 : 0;
    }
    if (tid == 0) stot = 0;
    __syncthreads();
    atomicAdd(&stot, cnt);
    __syncthreads();
  }
  const int isb = (stot * 2 > 1024) ? 1 : 0;

  // ---- scalar c with plausibility fallback ----
  float c;
  {
    unsigned short u0 = ((const unsigned short*)c_raw)[0];
    float cb = __uint_as_float(((unsigned int)u0) << 16);
    float cf = ((const float*)c_raw)[0];
    if (isb) c = (cb >= 1e-6f && cb <= 1e6f) ? cb : cf;
    else     c = (cf >= 1e-6f && cf <= 1e6f) ? cf : cb;
  }
  const float sc = sqrtf(c);

  // ---- expmap0(centroid_weight) -> LDS (threads 0..99) ----
  if (tid < K) {
    float u[C];
    float u2 = 0.f;
    #pragma unroll
    for (int i = 0; i < C; ++i) {
      u[i] = ldin(cw_raw, (size_t)tid * C + i, isb);
      u2 = fmaf(u[i], u[i], u2);
    }
    float nrm = fmaxf(sqrtf(u2), MIN_NORM);
    float f = tanhf(sc * nrm) / (sc * nrm);
    #pragma unroll
    for (int i = 0; i < C; ++i) yl[tid][i] = f * u[i];
    y2l[tid] = f * f * u2;
  }

  // ---- stage x vectors: NPB*T*C = 768 floats; float4 path when fp32 ----
  if (!isb) {
    const float* xf = (const float*)x_raw;
    // 192 float4 loads; thread idx covers (nl,t,cc4)
    for (int idx = tid; idx < NPB * T * (C / 4); idx += 256) {
      int nl = idx / (T * (C / 4));
      int r  = idx - nl * (T * (C / 4));
      int t  = r / (C / 4);
      int c4 = r - t * (C / 4);
      int n  = n0 + nl;
      float4 v = make_float4(0.f, 0.f, 0.f, 0.f);
      if (n < N)
        v = *(const float4*)(xf + ((((size_t)(b * T + t)) * N + n) * C + 4 * c4));
      xl[nl][t][4 * c4 + 0] = v.x;
      xl[nl][t][4 * c4 + 1] = v.y;
      xl[nl][t][4 * c4 + 2] = v.z;
      xl[nl][t][4 * c4 + 3] = v.w;
    }
  } else {
    for (int idx = tid; idx < NPB * T * C; idx += 256) {
      int nl = idx / (T * C);
      int r  = idx - nl * (T * C);
      int t  = r / C;
      int cc = r - t * C;
      int n  = n0 + nl;
      float v = 0.f;
      if (n < N) v = ldin(x_raw, (((size_t)(b * T + t)) * N + n) * C + cc, isb);
      xl[nl][t][cc] = v;
    }
  }
  __syncthreads();

  // ---- x squared norms ----
  if (tid < NPB * T) {
    int nl = tid / T, t = tid - nl * T;
    float s = 0.f;
    #pragma unroll
    for (int i = 0; i < C; ++i) s = fmaf(xl[nl][t][i], xl[nl][t][i], s);
    x2l[nl][t] = s;
  }
  __syncthreads();

  // ---- main: thread (grp,k) handles centroid k for node n0+grp ----
  const int grp = tid >> 7;
  const int k   = tid & 127;
  const int n   = n0 + grp;
  if (k < K && n < N) {
    float yk[C];
    #pragma unroll
    for (int i = 0; i < C; ++i) yk[i] = yl[k][i];
    const float y2 = y2l[k];
    const float c2 = c * c;
    float s = 0.f;
    #pragma unroll
    for (int t = 0; t < T; ++t) {
      float dot = 0.f;
      #pragma unroll
      for (int i = 0; i < C; ++i) dot = fmaf(xl[grp][t][i], yk[i], dot);
      const float x2 = x2l[grp][t];
      const float xy = -dot;                              // dot(-x, y)
      const float A  = fmaf(2.f * c, xy, 1.f) + c * y2;   // 1 + 2c*xy + c*y2
      const float Bc = 1.f - c * x2;                      // 1 - c*x2
      float num2 = A * A * x2 + Bc * Bc * y2 + 2.f * A * Bc * xy;
      float den  = fmaf(c2 * x2, y2, fmaf(2.f * c, xy, 1.f));
      den = fmaxf(den, MIN_NORM);
      float man = sqrtf(fmaxf(num2, 0.f)) / den;
      float arg = fminf(sc * man, 1.f - EPSF);
      arg = fmaxf(arg, -1.f + EPSF);
      float at = atanhf(arg);
      float dist = (2.f / sc) * at;
      float d2 = dist * dist;
      s += d2;
      out1[(((size_t)(b * T + t)) * N + n) * K + k] = d2;
    }
    out0[((size_t)b * N + n) * K + k] = s / (float)N;
  }
}

extern "C" void kernel_launch(void* const* d_in, const int* in_sizes, int n_in,
                              void* d_out, int out_size, void* d_ws, size_t ws_size,
                              hipStream_t stream) {
  // Identify inputs BY SIZE (order-proof): node 998400, centroids 3200, c 1.
  const void* xp = nullptr;
  const void* cwp = nullptr;
  const void* cp = nullptr;
  for (int i = 0; i < n_in; ++i) {
    if (in_sizes[i] == B * T * N * C)      xp  = d_in[i];
    else if (in_sizes[i] == K * C)         cwp = d_in[i];
    else if (in_sizes[i] == 1)             cp  = d_in[i];
  }
  if (!xp)  xp  = d_in[0];
  if (!cwp) cwp = d_in[1];
  if (!cp)  cp  = d_in[n_in - 1];

  float* out0 = (float*)d_out;                 // [B,N,K] fp32
  float* out1 = out0 + (size_t)B * N * K;      // [B,T,N,K] fp32
  dim3 grid(B * NPAIRS), block(256);
  hipLaunchKernelGGL(hcd_kernel, grid, block, 0, stream, xp, cwp, cp, out0, out1);
}

// Round 5
// 26.082 us; speedup vs baseline: 1.5005x; 1.5005x over previous
//
#include <hip/hip_runtime.h>

namespace {
constexpr int B = 8, T = 12, N = 325, C = 32, K = 100;
constexpr int KPAD = 33;                      // odd stride -> conflict-free LDS
constexpr int NPB = 2;                        // nodes per block
constexpr int NPAIRS = (N + NPB - 1) / NPB;   // 163
constexpr float EPSF = 1e-5f;
constexpr float MIN_NORM = 1e-15f;
}

// ---------- kernel 1: expmap0(centroids) -> d_ws (K*C floats y, K floats y2)
__global__ __launch_bounds__(128) void hcd_pre(
    const float* __restrict__ cw, const float* __restrict__ cptr,
    float* __restrict__ ws)
{
  const int k = threadIdx.x;
  if (k >= K) return;
  const float c = cptr[0];
  const float sc = sqrtf(c);
  float u[C];
  float u2 = 0.f;
  #pragma unroll
  for (int q = 0; q < C / 4; ++q) {
    float4 v = *(const float4*)(cw + k * C + 4 * q);
    u[4*q+0] = v.x; u[4*q+1] = v.y; u[4*q+2] = v.z; u[4*q+3] = v.w;
  }
  #pragma unroll
  for (int i = 0; i < C; ++i) u2 = fmaf(u[i], u[i], u2);
  float nrm = fmaxf(sqrtf(u2), MIN_NORM);
  float f = tanhf(sc * nrm) / (sc * nrm);    // precise; runs 100x total
  #pragma unroll
  for (int q = 0; q < C / 4; ++q) {
    float4 v = make_float4(f*u[4*q+0], f*u[4*q+1], f*u[4*q+2], f*u[4*q+3]);
    *(float4*)(ws + k * C + 4 * q) = v;
  }
  ws[K * C + k] = f * f * u2;
}

// ---------- kernel 2: fused distances
__global__ __launch_bounds__(256) void hcd_main(
    const float* __restrict__ x_g,       // [B,T,N,C]
    const float* __restrict__ ws,        // y[K*C], y2[K]
    const float* __restrict__ cptr,
    float* __restrict__ out0,            // [B,N,K]
    float* __restrict__ out1)            // [B,T,N,K]
{
  __shared__ float yl[K][KPAD];
  __shared__ float y2l[K];
  __shared__ float xl[NPB][T][KPAD];
  __shared__ float x2l[NPB][T];

  const int tid = threadIdx.x;
  const int b  = blockIdx.x / NPAIRS;
  const int np = blockIdx.x % NPAIRS;
  const int n0 = np * NPB;
  const float c  = cptr[0];
  const float sc = sqrtf(c);
  const float inv_c4 = 4.f / c;                 // (2/sc)^2
  const float HLN2 = 0.34657359028f;            // ln2/2

  // stage y: 800 float4 loads
  for (int idx = tid; idx < K * (C / 4); idx += 256) {
    int k = idx >> 3, q = idx & 7;
    float4 v = *(const float4*)(ws + k * C + 4 * q);
    yl[k][4*q+0] = v.x; yl[k][4*q+1] = v.y; yl[k][4*q+2] = v.z; yl[k][4*q+3] = v.w;
  }
  if (tid < K) y2l[tid] = ws[K * C + tid];

  // stage x: NPB*T*8 = 192 float4 loads
  for (int idx = tid; idx < NPB * T * (C / 4); idx += 256) {
    int nl = idx / (T * (C / 4));
    int r  = idx - nl * (T * (C / 4));
    int t  = r >> 3;
    int q  = r & 7;
    int n  = n0 + nl;
    float4 v = make_float4(0.f, 0.f, 0.f, 0.f);
    if (n < N)
      v = *(const float4*)(x_g + ((((size_t)(b * T + t)) * N + n) * C + 4 * q));
    xl[nl][t][4*q+0] = v.x; xl[nl][t][4*q+1] = v.y;
    xl[nl][t][4*q+2] = v.z; xl[nl][t][4*q+3] = v.w;
  }
  __syncthreads();

  if (tid < NPB * T) {
    int nl = tid / T, t = tid - nl * T;
    float s = 0.f;
    #pragma unroll
    for (int i = 0; i < C; ++i) s = fmaf(xl[nl][t][i], xl[nl][t][i], s);
    x2l[nl][t] = s;
  }
  __syncthreads();

  const int grp = tid >> 7;
  const int k   = tid & 127;
  const int n   = n0 + grp;
  if (k < K && n < N) {
    float yk[C];
    #pragma unroll
    for (int i = 0; i < C; ++i) yk[i] = yl[k][i];
    const float y2 = y2l[k];
    const float c2 = c * c;
    const float tc = 2.f * c;
    float s = 0.f;
    #pragma unroll
    for (int t = 0; t < T; ++t) {
      float dot = 0.f;
      #pragma unroll
      for (int i = 0; i < C; ++i) dot = fmaf(xl[grp][t][i], yk[i], dot);
      const float x2 = x2l[grp][t];
      const float xy = -dot;                              // dot(-x, y)
      const float A  = fmaf(tc, xy, 1.f) + c * y2;        // 1 + 2c*xy + c*y2
      const float Bc = 1.f - c * x2;                      // 1 - c*x2
      float num2 = A * A * x2 + Bc * Bc * y2 + 2.f * A * Bc * xy;
      num2 = fmaxf(num2, 0.f);
      float den  = fmaf(c2 * x2, y2, fmaf(tc, xy, 1.f));
      den = fmaxf(den, MIN_NORM);
      // z = sc * ||ma|| = sc * sqrt(num2) / den   (z >= 0)
      float z = sc * __builtin_amdgcn_sqrtf(num2) * __builtin_amdgcn_rcpf(den);
      z = fminf(z, 1.f - EPSF);
      // atanh(z) = (ln2/2) * log2((1+z)/(1-z))
      float r  = (1.f + z) * __builtin_amdgcn_rcpf(1.f - z);
      float at = HLN2 * __builtin_amdgcn_logf(r);
      float d2 = inv_c4 * at * at;
      s += d2;
      out1[(((size_t)(b * T + t)) * N + n) * K + k] = d2;
    }
    out0[((size_t)b * N + n) * K + k] = s * (1.f / (float)N);
  }
}

extern "C" void kernel_launch(void* const* d_in, const int* in_sizes, int n_in,
                              void* d_out, int out_size, void* d_ws, size_t ws_size,
                              hipStream_t stream) {
  // identify inputs by size (order-proof): node 998400, centroids 3200, c 1
  const void* xp = nullptr; const void* cwp = nullptr; const void* cp = nullptr;
  for (int i = 0; i < n_in; ++i) {
    if (in_sizes[i] == B * T * N * C)      xp  = d_in[i];
    else if (in_sizes[i] == K * C)         cwp = d_in[i];
    else if (in_sizes[i] == 1)             cp  = d_in[i];
  }
  if (!xp)  xp  = d_in[0];
  if (!cwp) cwp = d_in[1];
  if (!cp)  cp  = d_in[n_in - 1];

  float* ws   = (float*)d_ws;                  // K*C + K floats
  float* out0 = (float*)d_out;                 // [B,N,K]
  float* out1 = out0 + (size_t)B * N * K;      // [B,T,N,K]

  hipLaunchKernelGGL(hcd_pre, dim3(1), dim3(128), 0, stream,
                     (const float*)cwp, (const float*)cp, ws);
  hipLaunchKernelGGL(hcd_main, dim3(B * NPAIRS), dim3(256), 0, stream,
                     (const float*)xp, ws, (const float*)cp, out0, out1);
}

// Round 6
// 21.075 us; speedup vs baseline: 1.8570x; 1.2376x over previous
//
#include <hip/hip_runtime.h>

namespace {
constexpr int B = 8, T = 12, N = 325, C = 32, K = 100;
constexpr int KPAD = 33;                      // odd stride -> conflict-free LDS
constexpr int NPB = 5;                        // nodes per block; 325 = 5*65 exactly
constexpr int NPAIRS = N / NPB;               // 65
constexpr float EPSF = 1e-5f;
constexpr float MIN_NORM = 1e-15f;
}

__global__ __launch_bounds__(512) void hcd_kernel(
    const float* __restrict__ x_g,       // [B,T,N,C]
    const float* __restrict__ cw,        // [K,C]
    const float* __restrict__ cptr,      // [1]
    float* __restrict__ out0,            // [B,N,K]
    float* __restrict__ out1)            // [B,T,N,K]
{
  __shared__ float yl[K][KPAD];
  __shared__ float y2l[K];
  __shared__ float xl[NPB][T][KPAD];
  __shared__ float x2l[NPB][T];

  const int tid = threadIdx.x;
  const int b  = blockIdx.x / NPAIRS;
  const int np = blockIdx.x % NPAIRS;
  const int n0 = np * NPB;
  const float c  = cptr[0];
  const float sc = sqrtf(c);
  const float inv_c4 = 4.f / c;                 // (2/sc)^2
  const float HLN2 = 0.34657359028f;            // ln2/2
  const float TLOG2E = 2.88539008178f;          // 2*log2(e)

  // ---- expmap0(centroids) in-block, threads 0..99 (fast tanh via exp2) ----
  if (tid < K) {
    float u[C];
    float u2 = 0.f;
    #pragma unroll
    for (int q = 0; q < C / 4; ++q) {
      float4 v = *(const float4*)(cw + tid * C + 4 * q);
      u[4*q+0] = v.x; u[4*q+1] = v.y; u[4*q+2] = v.z; u[4*q+3] = v.w;
    }
    #pragma unroll
    for (int i = 0; i < C; ++i) u2 = fmaf(u[i], u[i], u2);
    float z = sc * fmaxf(sqrtf(u2), MIN_NORM);
    // tanh(z) = (E-1)/(E+1), E = e^{2z} = 2^{z*2log2e}
    float E  = exp2f(z * TLOG2E);
    float th = (E - 1.f) * __builtin_amdgcn_rcpf(E + 1.f);
    float f  = th * __builtin_amdgcn_rcpf(z);
    #pragma unroll
    for (int i = 0; i < C; ++i) yl[tid][i] = f * u[i];
    y2l[tid] = f * f * u2;
  }

  // ---- stage x: NPB*T*(C/4) = 480 float4 loads ----
  for (int idx = tid; idx < NPB * T * (C / 4); idx += 512) {
    int nl = idx / (T * (C / 4));
    int r  = idx - nl * (T * (C / 4));
    int t  = r >> 3;
    int q  = r & 7;
    int n  = n0 + nl;                       // always < N (325 = 5*65)
    float4 v = *(const float4*)(x_g + ((((size_t)(b * T + t)) * N + n) * C + 4 * q));
    xl[nl][t][4*q+0] = v.x; xl[nl][t][4*q+1] = v.y;
    xl[nl][t][4*q+2] = v.z; xl[nl][t][4*q+3] = v.w;
  }
  __syncthreads();

  // ---- x squared norms (threads 0..59) ----
  if (tid < NPB * T) {
    int nl = tid / T, t = tid - nl * T;
    float s = 0.f;
    #pragma unroll
    for (int i = 0; i < C; ++i) s = fmaf(xl[nl][t][i], xl[nl][t][i], s);
    x2l[nl][t] = s;
  }
  __syncthreads();

  // ---- main: thread = (grp, k); 500/512 active ----
  const int grp = tid / K;        // 0..5
  const int k   = tid - grp * K;  // 0..99
  if (grp < NPB) {
    const int n = n0 + grp;
    float yk[C];
    #pragma unroll
    for (int i = 0; i < C; ++i) yk[i] = yl[k][i];
    const float y2 = y2l[k];
    const float c2 = c * c;
    const float tc = 2.f * c;
    float s = 0.f;
    #pragma unroll
    for (int t = 0; t < T; ++t) {
      float dot = 0.f;
      #pragma unroll
      for (int i = 0; i < C; ++i) dot = fmaf(xl[grp][t][i], yk[i], dot);
      const float x2 = x2l[grp][t];
      const float xy = -dot;                              // dot(-x, y)
      const float A  = fmaf(tc, xy, 1.f) + c * y2;        // 1 + 2c*xy + c*y2
      const float Bc = 1.f - c * x2;                      // 1 - c*x2
      float num2 = A * A * x2 + Bc * Bc * y2 + 2.f * A * Bc * xy;
      num2 = fmaxf(num2, 0.f);
      float den  = fmaf(c2 * x2, y2, fmaf(tc, xy, 1.f));
      den = fmaxf(den, MIN_NORM);
      float z = sc * __builtin_amdgcn_sqrtf(num2) * __builtin_amdgcn_rcpf(den);
      z = fminf(z, 1.f - EPSF);
      float r  = (1.f + z) * __builtin_amdgcn_rcpf(1.f - z);
      float at = HLN2 * __builtin_amdgcn_logf(r);
      float d2 = inv_c4 * at * at;
      s += d2;
      out1[(((size_t)(b * T + t)) * N + n) * K + k] = d2;
    }
    out0[((size_t)b * N + n) * K + k] = s * (1.f / (float)N);
  }
}

extern "C" void kernel_launch(void* const* d_in, const int* in_sizes, int n_in,
                              void* d_out, int out_size, void* d_ws, size_t ws_size,
                              hipStream_t stream) {
  // identify inputs by size (order-proof): node 998400, centroids 3200, c 1
  const void* xp = nullptr; const void* cwp = nullptr; const void* cp = nullptr;
  for (int i = 0; i < n_in; ++i) {
    if (in_sizes[i] == B * T * N * C)      xp  = d_in[i];
    else if (in_sizes[i] == K * C)         cwp = d_in[i];
    else if (in_sizes[i] == 1)             cp  = d_in[i];
  }
  if (!xp)  xp  = d_in[0];
  if (!cwp) cwp = d_in[1];
  if (!cp)  cp  = d_in[n_in - 1];

  float* out0 = (float*)d_out;                 // [B,N,K]
  float* out1 = out0 + (size_t)B * N * K;      // [B,T,N,K]

  hipLaunchKernelGGL(hcd_kernel, dim3(B * NPAIRS), dim3(512), 0, stream,
                     (const float*)xp, (const float*)cwp, (const float*)cp,
                     out0, out1);
}

// Round 7
// 17.296 us; speedup vs baseline: 2.2628x; 1.2185x over previous
//
#include <hip/hip_runtime.h>

namespace {
constexpr int B = 8, T = 12, N = 325, C = 32, K = 100;
constexpr int KPAD = 36;                      // 16B-aligned rows -> real ds_read_b128
constexpr int NPB = 5;                        // nodes per block; 325 = 5*65
constexpr int NPAIRS = N / NPB;               // 65
constexpr float EPSF = 1e-5f;
constexpr float MIN_NORM = 1e-15f;
}

__global__ __launch_bounds__(512, 2) void hcd_kernel(
    const float* __restrict__ x_g,       // [B,T,N,C]
    const float* __restrict__ cw,        // [K,C]
    const float* __restrict__ cptr,      // [1]
    float* __restrict__ out0,            // [B,N,K]
    float* __restrict__ out1)            // [B,T,N,K]
{
  __shared__ float yl[K][KPAD];
  __shared__ float y2l[K];
  __shared__ float xl[NPB][T][KPAD];
  __shared__ float x2l[NPB][T];

  const int tid = threadIdx.x;
  const int b  = blockIdx.x / NPAIRS;
  const int np = blockIdx.x % NPAIRS;
  const int n0 = np * NPB;
  const float c  = cptr[0];
  const float sc = sqrtf(c);
  const float inv_c4 = 4.f / c;                 // (2/sqrt(c))^2
  const float HLN2 = 0.34657359028f;            // ln2/2
  const float TLOG2E = 2.88539008178f;          // 2*log2(e)

  // ---- stage x: 480 float4 loads (coalesced, one per thread) ----
  for (int idx = tid; idx < NPB * T * (C / 4); idx += 512) {
    int nl = idx / (T * (C / 4));
    int r  = idx - nl * (T * (C / 4));
    int t  = r >> 3;
    int q  = r & 7;
    int n  = n0 + nl;
    float4 v = *(const float4*)(x_g + ((((size_t)(b * T + t)) * N + n) * C + 4 * q));
    *(float4*)&xl[nl][t][4 * q] = v;
  }

  // ---- expmap0(centroids), threads 0..99 (overlaps staging latency) ----
  if (tid < K) {
    float u[C];
    float u2 = 0.f;
    #pragma unroll
    for (int q = 0; q < C / 4; ++q) {
      float4 v = *(const float4*)(cw + tid * C + 4 * q);
      u[4*q+0] = v.x; u[4*q+1] = v.y; u[4*q+2] = v.z; u[4*q+3] = v.w;
    }
    #pragma unroll
    for (int i = 0; i < C; ++i) u2 = fmaf(u[i], u[i], u2);
    float z = sc * fmaxf(sqrtf(u2), MIN_NORM);
    float E  = exp2f(z * TLOG2E);                       // e^(2z)
    float th = (E - 1.f) * __builtin_amdgcn_rcpf(E + 1.f);
    float f  = th * __builtin_amdgcn_rcpf(z);
    #pragma unroll
    for (int q = 0; q < C / 4; ++q) {
      float4 v = make_float4(f*u[4*q+0], f*u[4*q+1], f*u[4*q+2], f*u[4*q+3]);
      *(float4*)&yl[tid][4 * q] = v;
    }
    y2l[tid] = f * f * u2;
  }
  __syncthreads();

  // ---- x squared norms (threads 0..59) ----
  if (tid < NPB * T) {
    int nl = tid / T, t = tid - nl * T;
    float s = 0.f;
    #pragma unroll
    for (int i = 0; i < C; ++i) s = fmaf(xl[nl][t][i], xl[nl][t][i], s);
    x2l[nl][t] = s;
  }
  __syncthreads();

  // ---- main: thread = (grp, k); 500/512 active ----
  const int grp = tid / K;        // 0..5
  const int k   = tid - grp * K;  // 0..99
  if (grp < NPB) {
    const int n = n0 + grp;

    float yk[C];
    #pragma unroll
    for (int q = 0; q < C / 4; ++q) {
      float4 v = *(const float4*)&yl[k][4 * q];
      yk[4*q+0] = v.x; yk[4*q+1] = v.y; yk[4*q+2] = v.z; yk[4*q+3] = v.w;
    }
    const float y2 = y2l[k];
    const float c2 = c * c;
    const float tc = 2.f * c;

    // 12 independent dot accumulators: q-outer, t-inner for ILP
    float d[T];
    #pragma unroll
    for (int t = 0; t < T; ++t) d[t] = 0.f;
    #pragma unroll
    for (int q = 0; q < C / 4; ++q) {
      #pragma unroll
      for (int t = 0; t < T; ++t) {
        float4 xv = *(const float4*)&xl[grp][t][4 * q];
        float acc = d[t];
        acc = fmaf(xv.x, yk[4*q+0], acc);
        acc = fmaf(xv.y, yk[4*q+1], acc);
        acc = fmaf(xv.z, yk[4*q+2], acc);
        acc = fmaf(xv.w, yk[4*q+3], acc);
        d[t] = acc;
      }
    }

    // 12 independent epilogues
    float ssum = 0.f;
    #pragma unroll
    for (int t = 0; t < T; ++t) {
      const float x2 = x2l[grp][t];
      const float xy = -d[t];                             // dot(-x, y)
      const float A  = fmaf(tc, xy, 1.f) + c * y2;        // 1 + 2c*xy + c*y2
      const float Bc = 1.f - c * x2;                      // 1 - c*x2
      float num2 = A * A * x2 + Bc * Bc * y2 + 2.f * A * Bc * xy;
      num2 = fmaxf(num2, 0.f);
      float den = fmaf(c2 * x2, y2, fmaf(tc, xy, 1.f));
      den = fmaxf(den, MIN_NORM);
      float s_ = sc * __builtin_amdgcn_sqrtf(num2);
      s_ = fminf(s_, (1.f - EPSF) * den);                 // z <= 1-eps
      float r  = (den + s_) * __builtin_amdgcn_rcpf(den - s_);
      float at = HLN2 * __builtin_amdgcn_logf(r);         // atanh(z)
      float d2 = inv_c4 * at * at;
      ssum += d2;
      out1[(((size_t)(b * T + t)) * N + n) * K + k] = d2;
    }
    out0[((size_t)b * N + n) * K + k] = ssum * (1.f / (float)N);
  }
}

extern "C" void kernel_launch(void* const* d_in, const int* in_sizes, int n_in,
                              void* d_out, int out_size, void* d_ws, size_t ws_size,
                              hipStream_t stream) {
  // identify inputs by size (order-proof): node 998400, centroids 3200, c 1
  const void* xp = nullptr; const void* cwp = nullptr; const void* cp = nullptr;
  for (int i = 0; i < n_in; ++i) {
    if (in_sizes[i] == B * T * N * C)      xp  = d_in[i];
    else if (in_sizes[i] == K * C)         cwp = d_in[i];
    else if (in_sizes[i] == 1)             cp  = d_in[i];
  }
  if (!xp)  xp  = d_in[0];
  if (!cwp) cwp = d_in[1];
  if (!cp)  cp  = d_in[n_in - 1];

  float* out0 = (float*)d_out;                 // [B,N,K]
  float* out1 = out0 + (size_t)B * N * K;      // [B,T,N,K]

  hipLaunchKernelGGL(hcd_kernel, dim3(B * NPAIRS), dim3(512), 0, stream,
                     (const float*)xp, (const float*)cwp, (const float*)cp,
                     out0, out1);
}